// Round 8
// baseline (6642.046 us; speedup 1.0000x reference)
//
#include <hip/hip_runtime.h>

typedef unsigned short u16;
typedef unsigned int u32;
typedef __bf16 bf16x8 __attribute__((ext_vector_type(8)));
typedef float f32x4 __attribute__((ext_vector_type(4)));

#define B_ 256
#define T_ 128
#define E_ 300
#define EP 320
#define H_ 2048
#define G_ 8192

// ws layout (bytes) -- R1/R7-verified
#define OFF_XBF   0UL           // [T][B][EP] bf16           = 20,971,520
#define OFF_WPK   20971520UL    // 256 blk x 131072 B packed W_hh frags = 33,554,432
#define OFF_WIP   54525952UL    // 256 blk x 20480 B packed W_ih frags  =  5,242,880
#define OFF_BIAS  59768832UL    // 8192 f32
#define OFF_HBUF  59801600UL    // 2 x [256][2048] bf16
#define OFF_BAR   61898752UL    // 128 u32 step counters

// plain global->LDS, 16B per lane, lane-linear dest
#define GLDS16(gp, sp)                                                    \
  __builtin_amdgcn_global_load_lds(                                       \
      (__attribute__((address_space(1))) void*)(void*)(gp),               \
      (__attribute__((address_space(3))) void*)(sp), 16, 0, 0)

__device__ __forceinline__ u16 f2bf(float f) {
  u32 u = __builtin_bit_cast(u32, f);
  return (u16)((u + 0x7FFFu + ((u >> 16) & 1u)) >> 16);
}
__device__ __forceinline__ float sigm_f(float x) {
  return __builtin_amdgcn_rcpf(1.0f + __expf(-x));
}
__device__ __forceinline__ float tanh_f(float x) {
  return 1.0f - 2.0f * __builtin_amdgcn_rcpf(1.0f + __expf(2.0f * x));
}

// ---------------- prep: R1/R7-verified frag packing ----------------
// W_hh packed per block bid (8 h-cols j0=bid*8): [kt 0..63][f 0..1][lane][8]
//   lane ln -> col n=ln&15: gate = f*2 + (n>>3), c = n&7 ; k = kt*32 + (ln>>4)*8 + e
// W_ih packed identically with kt 0..9 over EP=320 (zero-pad past E=300).
__global__ void prep_kernel(const float* __restrict__ x, const float* __restrict__ Wih,
                            const float* __restrict__ Whh, const float* __restrict__ bih,
                            const float* __restrict__ bhh, u16* __restrict__ xbf,
                            u16* __restrict__ wpk, u16* __restrict__ wip,
                            float* __restrict__ biasc, u32* __restrict__ bar) {
  const long NX = (long)T_ * B_ * EP;
  const long NWPK = 256L * 65536L;
  const long NWIP = 256L * 10240L;
  const long NBS = G_;
  const long NBAR = T_;
  const long total = NX + NWPK + NWIP + NBS + NBAR;
  for (long q = (long)blockIdx.x * blockDim.x + threadIdx.x; q < total;
       q += (long)gridDim.x * blockDim.x) {
    long r = q;
    if (r < NX) {
      int t = (int)(r / (B_ * EP));
      int rem = (int)(r % (B_ * EP));
      int b = rem / EP, e = rem % EP;
      float v = (e < E_) ? x[((long)b * T_ + t) * E_ + e] : 0.0f;
      xbf[r] = f2bf(v);
    } else if ((r -= NX) < NWPK) {
      int blk = (int)(r >> 16);
      int qq = (int)(r & 65535);
      int e = qq & 7, ln = (qq >> 3) & 63, f = (qq >> 9) & 1, k2 = qq >> 10;
      int gate = f * 2 + ((ln >> 3) & 1);
      int grow = gate * H_ + blk * 8 + (ln & 7);
      int k = k2 * 32 + ((ln >> 4) & 3) * 8 + e;
      wpk[r] = f2bf(Whh[(long)grow * H_ + k]);
    } else if ((r -= NWPK) < NWIP) {
      int blk = (int)(r / 10240);
      int qq = (int)(r % 10240);
      int e = qq & 7, ln = (qq >> 3) & 63, f = (qq >> 9) & 1, k2 = qq >> 10;
      int gate = f * 2 + ((ln >> 3) & 1);
      int grow = gate * H_ + blk * 8 + (ln & 7);
      int k = k2 * 32 + ((ln >> 4) & 3) * 8 + e;
      wip[r] = f2bf((k < E_) ? Wih[(long)grow * E_ + k] : 0.0f);
    } else if ((r -= NWIP) < NBS) {
      biasc[r] = bih[r] + bhh[r];
    } else {
      r -= NBS;
      bar[r] = 0;
    }
  }
}

// ---------------- main persistent LSTM kernel ----------------
// 256 blocks x 512 thr (8 waves), 1 block/CU. Block bid owns 8 h-cols
// (j0=bid*8): 32 gate-rows x K=2048 of W_hh = 128 KiB LDS-RESIDENT all 128
// steps; W_ih slice (20 KiB) also LDS-resident. Zero steady-state W traffic
// (R7-verified: FETCH 621 MB).
// Change vs R7 (one lever): A-operand (x_t / h_t rows) staged into REGISTERS
// with group double-buffering -- h phase = 8 groups x 8 ktiles; while group g
// computes (~600cy of ds_read+MFMA), group g+1's 16 global_load_dwordx4
// (16 KB/wave, 128 KB/CU) are in flight. 8x the MLP of R7's vmcnt(2) LDS
// dbuf, which stalled a full L3 latency every 100cy-ktile (49 us/step).
// Compiler tracks per-VGPR vmcnt exactly; program order guarantees the
// group-ahead issue. h coherence (R1/R7-verified): producer sc0sc1 stores;
// consumer flag-spin -> syncthreads -> agent-acquire fence -> cached loads.
__global__ void __launch_bounds__(512, 2)
lstm_kernel(const u16* __restrict__ xbf, const u16* __restrict__ wpk,
            const u16* __restrict__ wip, const float* __restrict__ biasc,
            u16* __restrict__ hbuf, u32* __restrict__ bar, float* __restrict__ out) {
  __shared__ __align__(16) u16 Wl[65536];    // 128 KB resident W_hh frags
  __shared__ __align__(16) u16 WIl[10240];   // 20 KB resident W_ih frags

  const int tid = threadIdx.x;
  const int l = tid & 63;
  const int w = tid >> 6;            // 8 waves
  const int bid = blockIdx.x;
  const int rowbase = w << 5;        // wave's 32 batch rows
  const int rl = l & 15;             // fragment row lane
  const int kb = (l >> 4) << 3;      // k-offset within 32-k tile
  const int jc = (bid << 3) + (l & 7);
  const int half = (l >> 3) & 1;     // 0: lane holds {i,g}; 1: {f,o}

  // ---- one-time: W_hh + W_ih -> LDS (frag-linear == lane-linear GLDS) ----
  {
    const u16* wsrc = wpk + ((size_t)bid << 16);
    u16* wdst = &Wl[w << 9];
#pragma unroll
    for (int i = 0; i < 16; ++i)
      GLDS16(wsrc + (i << 12) + (tid << 3), wdst + (i << 12));
    const u16* wisrc = wip + (size_t)bid * 10240;
    u16* widst = &WIl[w << 9];
#pragma unroll
    for (int i = 0; i < 2; ++i)
      GLDS16(wisrc + (i << 12) + (tid << 3), widst + (i << 12));
    if (tid < 256)                          // last 4 KB (waves 0..3 full)
      GLDS16(wisrc + 8192 + (tid << 3), &WIl[8192] + (w << 9));
  }
  const float bi = biasc[jc];
  const float bff = biasc[H_ + jc];
  const float bg = biasc[2 * H_ + jc];
  const float bo = biasc[3 * H_ + jc];
  asm volatile("s_waitcnt vmcnt(0)" ::: "memory");
  __syncthreads();

  float cst[2][4];
#pragma unroll
  for (int rf = 0; rf < 2; ++rf)
#pragma unroll
    for (int r = 0; r < 4; ++r) cst[rf][r] = 0.0f;

#pragma unroll 1
  for (int t = 0; t < T_; ++t) {
    const u16* hcur = hbuf + (size_t)(t & 1) * (B_ * H_);
    u16* hnxt = hbuf + (size_t)((t + 1) & 1) * (B_ * H_);
    const u16* xsrc = xbf + (size_t)t * (B_ * EP);

    f32x4 acc[2][2];                 // [rowtile][ntile-f]
#pragma unroll
    for (int i = 0; i < 2; ++i) {
      acc[i][0] = (f32x4){0.f, 0.f, 0.f, 0.f};
      acc[i][1] = (f32x4){0.f, 0.f, 0.f, 0.f};
    }

    // ---- x phase: load all 20 A-frags to regs, compute 10 ktiles.
    // Runs BEFORE the flag wait (no h dependency) -- hides producer skew.
    {
      const u16* xr0 = xsrc + (size_t)(rowbase + rl) * EP + kb;
      const u16* xr1 = xr0 + (size_t)16 * EP;
      bf16x8 xa[10], xb[10];
#pragma unroll
      for (int kt = 0; kt < 10; ++kt) {
        xa[kt] = *(const bf16x8*)(xr0 + (kt << 5));
        xb[kt] = *(const bf16x8*)(xr1 + (kt << 5));
      }
#pragma unroll
      for (int kt = 0; kt < 10; ++kt) {
        const u16* bp = &WIl[(kt << 10) + (l << 3)];
        bf16x8 b0 = *(const bf16x8*)bp;
        bf16x8 b1 = *(const bf16x8*)(bp + 512);
        acc[0][0] = __builtin_amdgcn_mfma_f32_16x16x32_bf16(xa[kt], b0, acc[0][0], 0, 0, 0);
        acc[0][1] = __builtin_amdgcn_mfma_f32_16x16x32_bf16(xa[kt], b1, acc[0][1], 0, 0, 0);
        acc[1][0] = __builtin_amdgcn_mfma_f32_16x16x32_bf16(xb[kt], b0, acc[1][0], 0, 0, 0);
        acc[1][1] = __builtin_amdgcn_mfma_f32_16x16x32_bf16(xb[kt], b1, acc[1][1], 0, 0, 0);
      }
    }

    // ---- h phase (skipped at t=0: h==0): 8 groups x 8 ktiles, reg dbuf ----
    if (t > 0) {
      if (tid == 0) {
        while (__hip_atomic_load(&bar[t - 1], __ATOMIC_RELAXED,
                                 __HIP_MEMORY_SCOPE_AGENT) < 256u)
          __builtin_amdgcn_s_sleep(2);
      }
      __syncthreads();
      // drop stale h from L1/L2; cheap: nothing persistent cached (W in LDS)
      __builtin_amdgcn_fence(__ATOMIC_ACQUIRE, "agent");

      const u16* hr0 = hcur + (size_t)(rowbase + rl) * H_ + kb;
      const u16* hr1 = hr0 + (size_t)16 * H_;

      bf16x8 pa[8], pb[8], qa[8], qb[8];   // 128 VGPR: 2 groups in flight
      auto loadG = [&](bf16x8 (&fa)[8], bf16x8 (&fb)[8], int g) {
#pragma unroll
        for (int j = 0; j < 8; ++j) {
          fa[j] = *(const bf16x8*)(hr0 + (((g << 3) + j) << 5));
          fb[j] = *(const bf16x8*)(hr1 + (((g << 3) + j) << 5));
        }
      };
      auto compG = [&](bf16x8 (&fa)[8], bf16x8 (&fb)[8], int g) {
#pragma unroll
        for (int j = 0; j < 8; ++j) {
          const u16* bp = &Wl[(((g << 3) + j) << 10) + (l << 3)];
          bf16x8 b0 = *(const bf16x8*)bp;
          bf16x8 b1 = *(const bf16x8*)(bp + 512);
          acc[0][0] = __builtin_amdgcn_mfma_f32_16x16x32_bf16(fa[j], b0, acc[0][0], 0, 0, 0);
          acc[0][1] = __builtin_amdgcn_mfma_f32_16x16x32_bf16(fa[j], b1, acc[0][1], 0, 0, 0);
          acc[1][0] = __builtin_amdgcn_mfma_f32_16x16x32_bf16(fb[j], b0, acc[1][0], 0, 0, 0);
          acc[1][1] = __builtin_amdgcn_mfma_f32_16x16x32_bf16(fb[j], b1, acc[1][1], 0, 0, 0);
        }
      };

      loadG(pa, pb, 0);
      loadG(qa, qb, 1);
#pragma unroll 1
      for (int g = 0; g < 3; ++g) {
        compG(pa, pb, 2 * g);            // waits pa/pb via compiler vmcnt
        loadG(pa, pb, 2 * g + 2);        // refill while qa/qb computes
        compG(qa, qb, 2 * g + 1);
        loadG(qa, qb, 2 * g + 3);
      }
      compG(pa, pb, 6);
      compG(qa, qb, 7);
    }

    // ---- pointwise (R1/R7-verified): frag0={i|f}(c), frag1={g|o}(c);
    // partner lane l^8 holds complementary gates; both halves redundant.
#pragma unroll
    for (int rf = 0; rf < 2; ++rf) {
#pragma unroll
      for (int r = 0; r < 4; ++r) {
        float v0 = acc[rf][0][r];
        float v1 = acc[rf][1][r];
        float p0 = __shfl_xor(v0, 8);
        float p1 = __shfl_xor(v1, 8);
        float iv = half ? p0 : v0;
        float fv = half ? v0 : p0;
        float gv = half ? p1 : v1;
        float ov = half ? v1 : p1;
        float ig = sigm_f(iv + bi);
        float fg = sigm_f(fv + bff);
        float gg = tanh_f(gv + bg);
        float og = sigm_f(ov + bo);
        float cc = fg * cst[rf][r] + ig * gg;
        cst[rf][r] = cc;
        float h = og * tanh_f(cc);
        int row = rowbase + (rf << 4) + ((l >> 4) << 2) + r;
        if (t < T_ - 1) {
          if ((l & 8) == 0) {
            u16 hv = f2bf(h);
            u16* hp = hnxt + (size_t)row * H_ + jc;
            asm volatile("global_store_short %0, %1, off sc0 sc1"
                         :: "v"(hp), "v"((u32)hv) : "memory");
          }
        } else {
          if ((l & 8) == 0) out[(size_t)row * H_ + jc] = h;
        }
      }
    }

    if (t < T_ - 1) {
      __builtin_amdgcn_s_waitcnt(0);      // h stores reached coherent point
      __syncthreads();                    // all 8 waves drained
      if (tid == 0)
        __hip_atomic_fetch_add(&bar[t], 1u, __ATOMIC_RELAXED,
                               __HIP_MEMORY_SCOPE_AGENT);
    }
  }
}

extern "C" void kernel_launch(void* const* d_in, const int* in_sizes, int n_in,
                              void* d_out, int out_size, void* d_ws, size_t ws_size,
                              hipStream_t stream) {
  const float* x = (const float*)d_in[0];
  const float* Wih = (const float*)d_in[1];
  const float* Whh = (const float*)d_in[2];
  const float* bih = (const float*)d_in[3];
  const float* bhh = (const float*)d_in[4];
  char* ws = (char*)d_ws;
  u16* xbf = (u16*)(ws + OFF_XBF);
  u16* wpk = (u16*)(ws + OFF_WPK);
  u16* wip = (u16*)(ws + OFF_WIP);
  float* biasc = (float*)(ws + OFF_BIAS);
  u16* hbuf = (u16*)(ws + OFF_HBUF);
  u32* bar = (u32*)(ws + OFF_BAR);
  float* out = (float*)d_out;

  hipLaunchKernelGGL(prep_kernel, dim3(2048), dim3(256), 0, stream,
                     x, Wih, Whh, bih, bhh, xbf, wpk, wip, biasc, bar);

  void* args[] = {(void*)&xbf, (void*)&wpk, (void*)&wip,
                  (void*)&biasc, (void*)&hbuf, (void*)&bar, (void*)&out};
  hipLaunchCooperativeKernel((void*)lstm_kernel, dim3(256), dim3(512), args, 0, stream);
}

// Round 9
// 4894.728 us; speedup vs baseline: 1.3570x; 1.3570x over previous
//
#include <hip/hip_runtime.h>

typedef unsigned short u16;
typedef unsigned int u32;
typedef __bf16 bf16x8 __attribute__((ext_vector_type(8)));
typedef float f32x4 __attribute__((ext_vector_type(4)));

#define B_ 256
#define T_ 128
#define E_ 300
#define EP 320
#define H_ 2048
#define G_ 8192
#define HRING 16

// ws layout (bytes)
#define OFF_XBF   0UL           // [T][B][EP] bf16           = 20,971,520
#define OFF_WPK   20971520UL    // 256 blk x 131072 B packed W_hh frags = 33,554,432
#define OFF_WIP   54525952UL    // 256 blk x 20480 B packed W_ih frags  =  5,242,880
#define OFF_BIAS  59768832UL    // 8192 f32
#define OFF_HBUF  59801600UL    // 16 x [256][2048] bf16 ring = 16,777,216
#define OFF_BAR   76578816UL    // 128 u32 step counters

// plain global->LDS, 16B per lane, lane-linear dest
#define GLDS16(gp, sp)                                                    \
  __builtin_amdgcn_global_load_lds(                                       \
      (__attribute__((address_space(1))) void*)(void*)(gp),               \
      (__attribute__((address_space(3))) void*)(sp), 16, 0, 0)

__device__ __forceinline__ u16 f2bf(float f) {
  u32 u = __builtin_bit_cast(u32, f);
  return (u16)((u + 0x7FFFu + ((u >> 16) & 1u)) >> 16);
}
__device__ __forceinline__ float sigm_f(float x) {
  return __builtin_amdgcn_rcpf(1.0f + __expf(-x));
}
__device__ __forceinline__ float tanh_f(float x) {
  return 1.0f - 2.0f * __builtin_amdgcn_rcpf(1.0f + __expf(2.0f * x));
}

// ---------------- prep: R1/R7-verified frag packing ----------------
// W_hh packed per block bid (8 h-cols j0=bid*8): [kt 0..63][f 0..1][lane][8]
//   lane ln -> col n=ln&15: gate = f*2 + (n>>3), c = n&7 ; k = kt*32 + (ln>>4)*8 + e
// W_ih packed identically with kt 0..9 over EP=320 (zero-pad past E=300).
__global__ void prep_kernel(const float* __restrict__ x, const float* __restrict__ Wih,
                            const float* __restrict__ Whh, const float* __restrict__ bih,
                            const float* __restrict__ bhh, u16* __restrict__ xbf,
                            u16* __restrict__ wpk, u16* __restrict__ wip,
                            float* __restrict__ biasc, u32* __restrict__ bar) {
  const long NX = (long)T_ * B_ * EP;
  const long NWPK = 256L * 65536L;
  const long NWIP = 256L * 10240L;
  const long NBS = G_;
  const long NBAR = T_;
  const long total = NX + NWPK + NWIP + NBS + NBAR;
  for (long q = (long)blockIdx.x * blockDim.x + threadIdx.x; q < total;
       q += (long)gridDim.x * blockDim.x) {
    long r = q;
    if (r < NX) {
      int t = (int)(r / (B_ * EP));
      int rem = (int)(r % (B_ * EP));
      int b = rem / EP, e = rem % EP;
      float v = (e < E_) ? x[((long)b * T_ + t) * E_ + e] : 0.0f;
      xbf[r] = f2bf(v);
    } else if ((r -= NX) < NWPK) {
      int blk = (int)(r >> 16);
      int qq = (int)(r & 65535);
      int e = qq & 7, ln = (qq >> 3) & 63, f = (qq >> 9) & 1, k2 = qq >> 10;
      int gate = f * 2 + ((ln >> 3) & 1);
      int grow = gate * H_ + blk * 8 + (ln & 7);
      int k = k2 * 32 + ((ln >> 4) & 3) * 8 + e;
      wpk[r] = f2bf(Whh[(long)grow * H_ + k]);
    } else if ((r -= NWPK) < NWIP) {
      int blk = (int)(r / 10240);
      int qq = (int)(r % 10240);
      int e = qq & 7, ln = (qq >> 3) & 63, f = (qq >> 9) & 1, k2 = qq >> 10;
      int gate = f * 2 + ((ln >> 3) & 1);
      int grow = gate * H_ + blk * 8 + (ln & 7);
      int k = k2 * 32 + ((ln >> 4) & 3) * 8 + e;
      wip[r] = f2bf((k < E_) ? Wih[(long)grow * E_ + k] : 0.0f);
    } else if ((r -= NWIP) < NBS) {
      biasc[r] = bih[r] + bhh[r];
    } else {
      r -= NBS;
      bar[r] = 0;
    }
  }
}

// ---------------- main persistent LSTM kernel ----------------
// 256 blocks x 512 thr (8 waves), 1 block/CU. Block bid owns 8 h-cols
// (j0=bid*8): 32 gate-rows x K=2048 of W_hh = 128 KiB LDS-RESIDENT all 128
// steps; W_ih slice (20 KiB) also LDS-resident (R7/R8-verified: FETCH 621MB).
// A-operand h_t: R8's register-group double-buffer (8 groups x 8 ktiles,
// 16 KB/wave in flight).
// Change vs R8 (one lever: h transport): 16-deep h RING + NO per-step fence.
// Slot t&15 is written exactly once (step t-1, sc0sc1 write-through -- never
// enters any L2) and read once (step t) -> consumer L2s can hold no stale
// line of it (within-run reuse is 15 steps ~ 480 MB of streaming traffic
// through the 4MB L2; cross-run killed by ONE agent-acquire fence at kernel
// start, which can only force refetch, never staleness). h reads are plain
// CACHED loads: first CU per XCD fills L2 from L3 (1 MB), remaining 31 CUs
// hit L2 -> h broadcast drops from 256 MB/step L3 (the R7/R8 pacer: every
// CU's staggered buffer_inv wiped neighbors' fills) to 8 MB/step L3.
__global__ void __launch_bounds__(512, 2)
lstm_kernel(const u16* __restrict__ xbf, const u16* __restrict__ wpk,
            const u16* __restrict__ wip, const float* __restrict__ biasc,
            u16* __restrict__ hbuf, u32* __restrict__ bar, float* __restrict__ out) {
  __shared__ __align__(16) u16 Wl[65536];    // 128 KB resident W_hh frags
  __shared__ __align__(16) u16 WIl[10240];   // 20 KB resident W_ih frags

  const int tid = threadIdx.x;
  const int l = tid & 63;
  const int w = tid >> 6;            // 8 waves
  const int bid = blockIdx.x;
  const int rowbase = w << 5;        // wave's 32 batch rows
  const int rl = l & 15;             // fragment row lane
  const int kb = (l >> 4) << 3;      // k-offset within 32-k tile
  const int jc = (bid << 3) + (l & 7);
  const int half = (l >> 3) & 1;     // 0: lane holds {i,g}; 1: {f,o}

  // ---- one-time: W_hh + W_ih -> LDS (frag-linear == lane-linear GLDS) ----
  {
    const u16* wsrc = wpk + ((size_t)bid << 16);
    u16* wdst = &Wl[w << 9];
#pragma unroll
    for (int i = 0; i < 16; ++i)
      GLDS16(wsrc + (i << 12) + (tid << 3), wdst + (i << 12));
    const u16* wisrc = wip + (size_t)bid * 10240;
    u16* widst = &WIl[w << 9];
#pragma unroll
    for (int i = 0; i < 2; ++i)
      GLDS16(wisrc + (i << 12) + (tid << 3), widst + (i << 12));
    if (tid < 256)                          // last 4 KB
      GLDS16(wisrc + 8192 + (tid << 3), &WIl[8192] + (w << 9));
  }
  const float bi = biasc[jc];
  const float bff = biasc[H_ + jc];
  const float bg = biasc[2 * H_ + jc];
  const float bo = biasc[3 * H_ + jc];
  asm volatile("s_waitcnt vmcnt(0)" ::: "memory");
  __syncthreads();
  // ONE-TIME cross-launch invalidate: drops any h-ring lines cached by a
  // previous launch. Within-launch coherence needs no fence (ring argument).
  __builtin_amdgcn_fence(__ATOMIC_ACQUIRE, "agent");

  float cst[2][4];
#pragma unroll
  for (int rf = 0; rf < 2; ++rf)
#pragma unroll
    for (int r = 0; r < 4; ++r) cst[rf][r] = 0.0f;

#pragma unroll 1
  for (int t = 0; t < T_; ++t) {
    const u16* hcur = hbuf + (size_t)(t & (HRING - 1)) * (B_ * H_);
    u16* hnxt = hbuf + (size_t)((t + 1) & (HRING - 1)) * (B_ * H_);
    const u16* xsrc = xbf + (size_t)t * (B_ * EP);

    f32x4 acc[2][2];                 // [rowtile][ntile-f]
#pragma unroll
    for (int i = 0; i < 2; ++i) {
      acc[i][0] = (f32x4){0.f, 0.f, 0.f, 0.f};
      acc[i][1] = (f32x4){0.f, 0.f, 0.f, 0.f};
    }

    // ---- x phase: load all 20 A-frags to regs, compute 10 ktiles.
    // Runs BEFORE the flag wait (no h dependency) -- hides producer skew.
    {
      const u16* xr0 = xsrc + (size_t)(rowbase + rl) * EP + kb;
      const u16* xr1 = xr0 + (size_t)16 * EP;
      bf16x8 xa[10], xb[10];
#pragma unroll
      for (int kt = 0; kt < 10; ++kt) {
        xa[kt] = *(const bf16x8*)(xr0 + (kt << 5));
        xb[kt] = *(const bf16x8*)(xr1 + (kt << 5));
      }
#pragma unroll
      for (int kt = 0; kt < 10; ++kt) {
        const u16* bp = &WIl[(kt << 10) + (l << 3)];
        bf16x8 b0 = *(const bf16x8*)bp;
        bf16x8 b1 = *(const bf16x8*)(bp + 512);
        acc[0][0] = __builtin_amdgcn_mfma_f32_16x16x32_bf16(xa[kt], b0, acc[0][0], 0, 0, 0);
        acc[0][1] = __builtin_amdgcn_mfma_f32_16x16x32_bf16(xa[kt], b1, acc[0][1], 0, 0, 0);
        acc[1][0] = __builtin_amdgcn_mfma_f32_16x16x32_bf16(xb[kt], b0, acc[1][0], 0, 0, 0);
        acc[1][1] = __builtin_amdgcn_mfma_f32_16x16x32_bf16(xb[kt], b1, acc[1][1], 0, 0, 0);
      }
    }

    // ---- h phase (skipped at t=0: h==0): 8 groups x 8 ktiles, reg dbuf ----
    if (t > 0) {
      if (tid == 0) {
        while (__hip_atomic_load(&bar[t - 1], __ATOMIC_RELAXED,
                                 __HIP_MEMORY_SCOPE_AGENT) < 256u)
          __builtin_amdgcn_s_sleep(2);
      }
      __syncthreads();
      // NO fence here: slot t&15 was never cached by this XCD's L2 (written
      // only via sc0sc1 write-through; last cached 15 steps ago -> evicted).
      // Cached loads dedup the broadcast in L2 across the XCD's 32 CUs.

      const u16* hr0 = hcur + (size_t)(rowbase + rl) * H_ + kb;
      const u16* hr1 = hr0 + (size_t)16 * H_;

      bf16x8 pa[8], pb[8], qa[8], qb[8];   // 128 VGPR: 2 groups in flight
      auto loadG = [&](bf16x8 (&fa)[8], bf16x8 (&fb)[8], int g) {
#pragma unroll
        for (int j = 0; j < 8; ++j) {
          fa[j] = *(const bf16x8*)(hr0 + (((g << 3) + j) << 5));
          fb[j] = *(const bf16x8*)(hr1 + (((g << 3) + j) << 5));
        }
      };
      auto compG = [&](bf16x8 (&fa)[8], bf16x8 (&fb)[8], int g) {
#pragma unroll
        for (int j = 0; j < 8; ++j) {
          const u16* bp = &Wl[(((g << 3) + j) << 10) + (l << 3)];
          bf16x8 b0 = *(const bf16x8*)bp;
          bf16x8 b1 = *(const bf16x8*)(bp + 512);
          acc[0][0] = __builtin_amdgcn_mfma_f32_16x16x32_bf16(fa[j], b0, acc[0][0], 0, 0, 0);
          acc[0][1] = __builtin_amdgcn_mfma_f32_16x16x32_bf16(fa[j], b1, acc[0][1], 0, 0, 0);
          acc[1][0] = __builtin_amdgcn_mfma_f32_16x16x32_bf16(fb[j], b0, acc[1][0], 0, 0, 0);
          acc[1][1] = __builtin_amdgcn_mfma_f32_16x16x32_bf16(fb[j], b1, acc[1][1], 0, 0, 0);
        }
      };

      loadG(pa, pb, 0);
      loadG(qa, qb, 1);
#pragma unroll 1
      for (int g = 0; g < 3; ++g) {
        compG(pa, pb, 2 * g);            // waits pa/pb via compiler vmcnt
        loadG(pa, pb, 2 * g + 2);        // refill while qa/qb computes
        compG(qa, qb, 2 * g + 1);
        loadG(qa, qb, 2 * g + 3);
      }
      compG(pa, pb, 6);
      compG(qa, qb, 7);
    }

    // ---- pointwise (R1/R7/R8-verified): frag0={i|f}(c), frag1={g|o}(c);
    // partner lane l^8 holds complementary gates; both halves redundant.
#pragma unroll
    for (int rf = 0; rf < 2; ++rf) {
#pragma unroll
      for (int r = 0; r < 4; ++r) {
        float v0 = acc[rf][0][r];
        float v1 = acc[rf][1][r];
        float p0 = __shfl_xor(v0, 8);
        float p1 = __shfl_xor(v1, 8);
        float iv = half ? p0 : v0;
        float fv = half ? v0 : p0;
        float gv = half ? p1 : v1;
        float ov = half ? v1 : p1;
        float ig = sigm_f(iv + bi);
        float fg = sigm_f(fv + bff);
        float gg = tanh_f(gv + bg);
        float og = sigm_f(ov + bo);
        float cc = fg * cst[rf][r] + ig * gg;
        cst[rf][r] = cc;
        float h = og * tanh_f(cc);
        int row = rowbase + (rf << 4) + ((l >> 4) << 2) + r;
        if (t < T_ - 1) {
          if ((l & 8) == 0) {
            u16 hv = f2bf(h);
            u16* hp = hnxt + (size_t)row * H_ + jc;
            asm volatile("global_store_short %0, %1, off sc0 sc1"
                         :: "v"(hp), "v"((u32)hv) : "memory");
          }
        } else {
          if ((l & 8) == 0) out[(size_t)row * H_ + jc] = h;
        }
      }
    }

    if (t < T_ - 1) {
      __builtin_amdgcn_s_waitcnt(0);      // h stores reached coherent point (L3)
      __syncthreads();                    // all 8 waves drained
      if (tid == 0)
        __hip_atomic_fetch_add(&bar[t], 1u, __ATOMIC_RELAXED,
                               __HIP_MEMORY_SCOPE_AGENT);
    }
  }
}

extern "C" void kernel_launch(void* const* d_in, const int* in_sizes, int n_in,
                              void* d_out, int out_size, void* d_ws, size_t ws_size,
                              hipStream_t stream) {
  const float* x = (const float*)d_in[0];
  const float* Wih = (const float*)d_in[1];
  const float* Whh = (const float*)d_in[2];
  const float* bih = (const float*)d_in[3];
  const float* bhh = (const float*)d_in[4];
  char* ws = (char*)d_ws;
  u16* xbf = (u16*)(ws + OFF_XBF);
  u16* wpk = (u16*)(ws + OFF_WPK);
  u16* wip = (u16*)(ws + OFF_WIP);
  float* biasc = (float*)(ws + OFF_BIAS);
  u16* hbuf = (u16*)(ws + OFF_HBUF);
  u32* bar = (u32*)(ws + OFF_BAR);
  float* out = (float*)d_out;

  hipLaunchKernelGGL(prep_kernel, dim3(2048), dim3(256), 0, stream,
                     x, Wih, Whh, bih, bhh, xbf, wpk, wip, biasc, bar);

  void* args[] = {(void*)&xbf, (void*)&wpk, (void*)&wip,
                  (void*)&biasc, (void*)&hbuf, (void*)&bar, (void*)&out};
  hipLaunchCooperativeKernel((void*)lstm_kernel, dim3(256), dim3(512), args, 0, stream);
}